// Round 1
// baseline (828.144 us; speedup 1.0000x reference)
//
#include <hip/hip_runtime.h>
#include <hip/hip_bf16.h>

// Problem constants (fixed by the reference setup)
#define EMB      64   // embedding dim (d)
#define INTERM   64   // EMB_INTERM (i)
#define NSPH     16   // num spherical (s)
#define KMAXC    24   // Kmax
#define KPAD     32   // padded K for MFMA (16x16x32)

// LDS row strides (elements, bf16). Multiples of 8 (16B) for ds_read_b128
// alignment; 40 and 72 give 2-way (free) bank aliasing instead of 16-way.
#define SPH_STRIDE 40   // 16 rows
#define M2_STRIDE  40   // 64 rows (transposed m2: [d][k])
#define RBF_STRIDE 72   // 16 rows (transposed rbf: [s][i])
#define W_STRIDE   72   // 64 rows ([d][i])

typedef __attribute__((ext_vector_type(8))) __bf16 bf16x8;
typedef __attribute__((ext_vector_type(8))) unsigned short u16x8;
typedef __attribute__((ext_vector_type(4))) float f32x4;

__device__ __forceinline__ unsigned short f2bf(float f) {
    union { float f; unsigned int u; } v;
    v.f = f;
    unsigned int u = v.u;
    // round-to-nearest-even bf16
    return (unsigned short)((u + 0x7FFFu + ((u >> 16) & 1u)) >> 16);
}

__device__ __forceinline__ bf16x8 lds_ld8(const unsigned short* p) {
    u16x8 v = *(const u16x8*)p;   // 16B-aligned by construction -> ds_read_b128
    return __builtin_bit_cast(bf16x8, v);
}

// Kernel 1: recover per-edge triplet ranges from id_reduce/Kidx.
// Triplets are sorted by edge; Kidx==0 marks the start, edge-boundary marks end.
__global__ void edge_index_kernel(const int* __restrict__ id_reduce,
                                  const int* __restrict__ Kidx,
                                  int* __restrict__ starts,
                                  int* __restrict__ counts,
                                  int nT) {
    int t = blockIdx.x * blockDim.x + threadIdx.x;
    if (t >= nT) return;
    int e = id_reduce[t];
    int k = Kidx[t];
    if (k == 0) starts[e] = t;
    if (t == nT - 1 || id_reduce[t + 1] != e) counts[e] = k + 1;
}

// Kernel 2: persistent blocks; per edge:
//   T(16x64) = sph(16x24,pad32) @ m2(24x64)          [1 mfma/wave]
//   A(16x64) = rbfT(16x64) @ W^T(64x64)              [2 mfma/wave]
//   m_ca[d]  = sum_s T[s,d]*A[s,d]                   [regs + shfl reduce]
__launch_bounds__(256, 8)
__global__ void eih_main_kernel(const float* __restrict__ rbf,
                                const float* __restrict__ sph,
                                const float* __restrict__ m,
                                const float* __restrict__ W,
                                const int* __restrict__ Kidx,
                                const int* __restrict__ starts,
                                const int* __restrict__ counts,
                                float* __restrict__ out,
                                int nE) {
    __shared__ __align__(16) unsigned short W_s[EMB * W_STRIDE];       // [d][i]
    __shared__ __align__(16) unsigned short rbfT_s[NSPH * RBF_STRIDE]; // [s][i]
    __shared__ __align__(16) unsigned short sph_s[NSPH * SPH_STRIDE];  // [s][k]
    __shared__ __align__(16) unsigned short m2T_s[EMB * M2_STRIDE];    // [d][k]

    const int tid  = threadIdx.x;
    const int lane = tid & 63;
    const int wave = tid >> 6;    // 0..3 -> n-tile (d in [16*wave, 16*wave+16))
    const int quad = lane >> 4;   // 0..3
    const int l16  = lane & 15;

    // ---- stage W once per block: 4096 floats -> bf16 [d][i]
    {
        int base = tid * 16;            // 16 consecutive floats per thread
        int d = base >> 6;              // tid/4
        int i0 = base & 63;             // (tid&3)*16
        const float4* Wv = (const float4*)(W + base);
        #pragma unroll
        for (int u = 0; u < 4; ++u) {
            float4 f = Wv[u];
            int i = i0 + u * 4;
            W_s[d * W_STRIDE + i + 0] = f2bf(f.x);
            W_s[d * W_STRIDE + i + 1] = f2bf(f.y);
            W_s[d * W_STRIDE + i + 2] = f2bf(f.z);
            W_s[d * W_STRIDE + i + 3] = f2bf(f.w);
        }
    }
    // (visibility of W_s covered by the in-loop post-staging barrier)

    for (int e = blockIdx.x; e < nE; e += gridDim.x) {
        const int start = starts[e];
        const int count = counts[e];

        // ---- stage sph: 384 floats -> sph_s[s][k]; zero-pad k in [24,32)
        if (tid < 96) {
            const float4* sv = (const float4*)(sph + (size_t)e * (NSPH * KMAXC)) + tid;
            float4 f = *sv;
            float vals[4] = {f.x, f.y, f.z, f.w};
            int flat = tid * 4;
            #pragma unroll
            for (int u = 0; u < 4; ++u) {
                int fl = flat + u;
                int s = fl / 24;
                int k = fl - s * 24;
                sph_s[s * SPH_STRIDE + k] = f2bf(vals[u]);
            }
        } else if (tid < 160) {
            int idx = tid - 96;           // 0..63 -> 16 rows x 4 word-pairs
            int s = idx >> 2;
            int k = 24 + ((idx & 3) << 1);
            sph_s[s * SPH_STRIDE + k]     = 0;
            sph_s[s * SPH_STRIDE + k + 1] = 0;
        }

        // ---- stage rbf (transpose): 1024 floats [i][s] -> rbfT_s[s][i]
        {
            const float4* rv = (const float4*)(rbf + (size_t)e * (INTERM * NSPH)) + tid;
            float4 f = *rv;
            int i = tid >> 2;
            int s0 = (tid & 3) * 4;
            rbfT_s[(s0 + 0) * RBF_STRIDE + i] = f2bf(f.x);
            rbfT_s[(s0 + 1) * RBF_STRIDE + i] = f2bf(f.y);
            rbfT_s[(s0 + 2) * RBF_STRIDE + i] = f2bf(f.z);
            rbfT_s[(s0 + 3) * RBF_STRIDE + i] = f2bf(f.w);
        }

        // ---- zero m2T slots k in [count, 32) (disjoint from gather writes)
        {
            int row = tid & 63;
            for (int k = count + (tid >> 6); k < KPAD; k += 4)
                m2T_s[row * M2_STRIDE + k] = 0;
        }

        // ---- gather m rows (contiguous per edge), transpose into m2T_s[d][k]
        {
            int nv = count * 16;          // float4 chunks
            const float4* mv = (const float4*)(m + (size_t)start * EMB);
            for (int t = tid; t < nv; t += 256) {
                float4 f = mv[t];
                int j = t >> 4;                   // triplet row within edge
                int dd = (t & 15) * 4;            // embedding base index
                int kslot = Kidx[start + j];      // slot (== j for this data)
                m2T_s[(dd + 0) * M2_STRIDE + kslot] = f2bf(f.x);
                m2T_s[(dd + 1) * M2_STRIDE + kslot] = f2bf(f.y);
                m2T_s[(dd + 2) * M2_STRIDE + kslot] = f2bf(f.z);
                m2T_s[(dd + 3) * M2_STRIDE + kslot] = f2bf(f.w);
            }
        }

        __syncthreads();

        // ---- G1: T-tile = sph @ m2   (one 16x16x32 MFMA per wave)
        f32x4 accT = {0.f, 0.f, 0.f, 0.f};
        {
            bf16x8 a = lds_ld8(&sph_s[l16 * SPH_STRIDE + quad * 8]);
            bf16x8 b = lds_ld8(&m2T_s[(wave * 16 + l16) * M2_STRIDE + quad * 8]);
            accT = __builtin_amdgcn_mfma_f32_16x16x32_bf16(a, b, accT, 0, 0, 0);
        }

        // ---- G2: A-tile = rbfT @ W^T  (K=64 -> two MFMAs)
        f32x4 accA = {0.f, 0.f, 0.f, 0.f};
        {
            bf16x8 a0 = lds_ld8(&rbfT_s[l16 * RBF_STRIDE + quad * 8]);
            bf16x8 b0 = lds_ld8(&W_s[(wave * 16 + l16) * W_STRIDE + quad * 8]);
            accA = __builtin_amdgcn_mfma_f32_16x16x32_bf16(a0, b0, accA, 0, 0, 0);
            bf16x8 a1 = lds_ld8(&rbfT_s[l16 * RBF_STRIDE + 32 + quad * 8]);
            bf16x8 b1 = lds_ld8(&W_s[(wave * 16 + l16) * W_STRIDE + 32 + quad * 8]);
            accA = __builtin_amdgcn_mfma_f32_16x16x32_bf16(a1, b1, accA, 0, 0, 0);
        }

        // ---- combine: p(lane) = sum over this quad's 4 s-rows; reduce quads
        float p = accT[0] * accA[0] + accT[1] * accA[1]
                + accT[2] * accA[2] + accT[3] * accA[3];
        p += __shfl_xor(p, 16, 64);
        p += __shfl_xor(p, 32, 64);
        if (quad == 0)
            out[(size_t)e * EMB + wave * 16 + l16] = p;

        __syncthreads();   // protect LDS from next edge's staging
    }
}

extern "C" void kernel_launch(void* const* d_in, const int* in_sizes, int n_in,
                              void* d_out, int out_size, void* d_ws, size_t ws_size,
                              hipStream_t stream) {
    const float* rbf       = (const float*)d_in[0]; // (nE, 64, 16)
    const float* sph       = (const float*)d_in[1]; // (nE, 16, 24)
    const float* m         = (const float*)d_in[2]; // (nT, 64)
    const float* W         = (const float*)d_in[3]; // (64, 1, 64)
    const int*   id_reduce = (const int*)d_in[4];   // (nT,)
    const int*   Kidx      = (const int*)d_in[5];   // (nT,)
    float* out = (float*)d_out;

    const int nE = in_sizes[0] / (INTERM * NSPH);
    const int nT = in_sizes[2] / EMB;

    int* starts = (int*)d_ws;
    int* counts = starts + nE;

    hipLaunchKernelGGL(edge_index_kernel, dim3((nT + 255) / 256), dim3(256), 0, stream,
                       id_reduce, Kidx, starts, counts, nT);

    int grid = 2048;             // 8 blocks/CU * 256 CUs (persistent)
    if (grid > nE) grid = nE;
    hipLaunchKernelGGL(eih_main_kernel, dim3(grid), dim3(256), 0, stream,
                       rbf, sph, m, W, Kidx, starts, counts, out, nE);
}